// Round 1
// baseline (1305.348 us; speedup 1.0000x reference)
//
#include <hip/hip_runtime.h>

#define NBINS 10
#define NCLASS 128

// Main pass: per-row max+argmax, bin, accumulate (count, conf_sum, acc_sum)
// into LDS, then one global-atomic flush per block.
// Layout of ws accumulators (float): [0..9]=count, [10..19]=conf_sum, [20..29]=acc_sum
__global__ __launch_bounds__(256) void rd_main(
    const float* __restrict__ soft,
    const int* __restrict__ labels,
    float* __restrict__ acc_ws,
    long long n_rows)
{
    __shared__ float s_cnt[NBINS];
    __shared__ float s_conf[NBINS];
    __shared__ float s_acc[NBINS];
    if (threadIdx.x < NBINS) {
        s_cnt[threadIdx.x]  = 0.0f;
        s_conf[threadIdx.x] = 0.0f;
        s_acc[threadIdx.x]  = 0.0f;
    }
    __syncthreads();

    const int wave_in_blk = threadIdx.x >> 6;   // 4 waves / block
    const int lane        = threadIdx.x & 63;
    const int half        = lane >> 5;          // 0: row 2p, 1: row 2p+1
    const int lane32      = lane & 31;

    const long long wave        = (long long)blockIdx.x * 4 + wave_in_blk;
    const long long total_waves = (long long)gridDim.x * 4;
    const long long n_pairs     = (n_rows + 1) >> 1;

    for (long long p = wave; p < n_pairs; p += total_waves) {
        const long long row = p * 2 + half;
        float bv = -1.0f;
        int   bi = 0;
        if (row < n_rows) {
            const float4* rp = (const float4*)(soft + row * (long long)NCLASS);
            float4 v = rp[lane32];              // 16B/lane, 1KiB/wave-instr
            const int c0 = lane32 * 4;
            bv = v.x; bi = c0;
            if (v.y > bv) { bv = v.y; bi = c0 + 1; }
            if (v.z > bv) { bv = v.z; bi = c0 + 2; }
            if (v.w > bv) { bv = v.w; bi = c0 + 3; }
        }
        // butterfly max+argmax within each 32-lane segment (first-max tie-break)
        #pragma unroll
        for (int mask = 1; mask < 32; mask <<= 1) {
            float ov = __shfl_xor(bv, mask, 32);
            int   oi = __shfl_xor(bi, mask, 32);
            if (ov > bv || (ov == bv && oi < bi)) { bv = ov; bi = oi; }
        }
        if (lane32 == 0 && row < n_rows) {
            const int lab = labels[row];
            const float acc = (bi == lab) ? 1.0f : 0.0f;
            int b = (int)ceilf(bv * 10.0f) - 1;
            b = b < 0 ? 0 : (b > NBINS - 1 ? NBINS - 1 : b);
            atomicAdd(&s_cnt[b],  1.0f);
            atomicAdd(&s_conf[b], bv);
            atomicAdd(&s_acc[b],  acc);
        }
    }
    __syncthreads();
    if (threadIdx.x < NBINS) {
        atomicAdd(&acc_ws[threadIdx.x],             s_cnt[threadIdx.x]);
        atomicAdd(&acc_ws[NBINS + threadIdx.x],     s_conf[threadIdx.x]);
        atomicAdd(&acc_ws[2 * NBINS + threadIdx.x], s_acc[threadIdx.x]);
    }
}

// Finalize: x[b] = conf_sum/count, y[b] = acc_sum/count (0 where count==0)
__global__ void rd_final(const float* __restrict__ acc_ws, float* __restrict__ out)
{
    const int t = threadIdx.x;
    if (t < NBINS) {
        const float c = acc_ws[t];
        out[t]         = (c > 0.0f) ? acc_ws[NBINS + t] / c     : 0.0f;
        out[NBINS + t] = (c > 0.0f) ? acc_ws[2 * NBINS + t] / c : 0.0f;
    }
}

extern "C" void kernel_launch(void* const* d_in, const int* in_sizes, int n_in,
                              void* d_out, int out_size, void* d_ws, size_t ws_size,
                              hipStream_t stream)
{
    const float* soft   = (const float*)d_in[0];
    const int*   labels = (const int*)d_in[1];
    float*       out    = (float*)d_out;
    float*       ws     = (float*)d_ws;

    const long long n_rows = (long long)in_sizes[1];  // labels count = N

    // zero the 30 float accumulators (ws is re-poisoned to 0xAA before each call)
    hipMemsetAsync(ws, 0, 3 * NBINS * sizeof(float), stream);

    // 2048 blocks x 4 waves = 8192 waves = device wave capacity
    rd_main<<<2048, 256, 0, stream>>>(soft, labels, ws, n_rows);
    rd_final<<<1, 64, 0, stream>>>(ws, out);
}